// Round 5
// baseline (440.220 us; speedup 1.0000x reference)
//
#include <hip/hip_runtime.h>

#define NB 8
#define NT 2048
#define NC 1024
#define HD 64
#define N3 192

typedef float f32x4 __attribute__((ext_vector_type(4)));
typedef _Float16 f16x8 __attribute__((ext_vector_type(8)));
typedef short short8 __attribute__((ext_vector_type(8)));
typedef short short4v __attribute__((ext_vector_type(4)));

static __device__ __forceinline__ short f2h(float f) {
  _Float16 h = (_Float16)f;
  return __builtin_bit_cast(short, h);
}
static __device__ __forceinline__ unsigned pk2h(float a, float b) {
  unsigned lo = (unsigned short)f2h(a);
  unsigned hi = (unsigned short)f2h(b);
  return lo | (hi << 16);
}

typedef __attribute__((address_space(1))) const void* gptr1;
typedef __attribute__((address_space(3))) void* sptr3;
static __device__ __forceinline__ void gload_lds16(const void* g, void* s) {
  __builtin_amdgcn_global_load_lds((gptr1)g, (sptr3)s, 16, 0, 0);
}

// ---- prep: W[1024][192] f32 -> Wt [192][1024] f16 (transposed); zero kmax2+cnt ----
__launch_bounds__(256)
__global__ void prep_w(const float* __restrict__ W, short* __restrict__ Wt,
                       float* __restrict__ kmax2, int* __restrict__ cnt) {
  if (blockIdx.x == 0) {
    if (threadIdx.x < 256) cnt[threadIdx.x] = 0;
    if (threadIdx.x < 8) kmax2[threadIdx.x] = 0.f;
  }
  const int n = threadIdx.x;
  if (n >= 192) return;
  const int k0 = blockIdx.x * 16;
  short8 v0, v1;
#pragma unroll
  for (int j = 0; j < 8; ++j) v0[j] = f2h(W[(size_t)(k0 + j) * N3 + n]);
#pragma unroll
  for (int j = 0; j < 8; ++j) v1[j] = f2h(W[(size_t)(k0 + 8 + j) * N3 + n]);
  *(short8*)(Wt + (size_t)n * NC + k0) = v0;
  *(short8*)(Wt + (size_t)n * NC + k0 + 8) = v1;
}

// ---- qkv projection: x[16384,1024]f32 @ W + b, fp16 single-term MFMA ----
__launch_bounds__(256, 2)
__global__ void qkv_proj(const float* __restrict__ x, const short* __restrict__ Wt,
                         const float* __restrict__ bias, short* __restrict__ Kb,
                         short* __restrict__ Qb, short* __restrict__ Vt,
                         float* __restrict__ kmax2) {
  __shared__ short Ax[2][32 * 64];    // [buf][m][k] swizzled (4KB each)
  __shared__ short Bw[2][192 * 64];   // [buf][n][k] swizzled (24KB each)

  const int tid = threadIdx.x;
  const int lane = tid & 63;
  const int wave = tid >> 6;
  const int wr = wave >> 1, wc = wave & 1;   // wave tile: 16 m-rows x 96 n-cols
  const int r0 = blockIdx.x * 32;
  const int batch = r0 >> 11;
  const int t0 = r0 & (NT - 1);
  const int g = lane >> 4, c = lane & 15;

  const int bsub = lane >> 3;
  const size_t bgoff = (size_t)bsub * (NC * 2) + (size_t)((lane & 7) ^ bsub) * 16;

  f32x4 acc[6];
#pragma unroll
  for (int nt = 0; nt < 6; ++nt) acc[nt] = (f32x4){0.f, 0.f, 0.f, 0.f};

  float4 areg[2];

  auto stage_B = [&](int kt, int p) {
    const char* src = (const char*)Wt + (size_t)(wave * 48) * (NC * 2) +
                      (size_t)kt * 128 + bgoff;
    char* dst = (char*)Bw[p] + wave * 48 * 128;
#pragma unroll
    for (int j = 0; j < 6; ++j)
      gload_lds16(src + (size_t)(j * 8) * (NC * 2), dst + j * 8 * 128);
  };
  auto load_A = [&](int kt) {
    const float* xp = x + (size_t)r0 * NC + kt * 64;
#pragma unroll
    for (int i = 0; i < 2; ++i) {
      int idx = tid + 256 * i;
      int row = idx >> 4, c4 = idx & 15;
      areg[i] = *(const float4*)(xp + (size_t)row * NC + c4 * 4);
    }
  };
  auto write_A = [&](int p) {
#pragma unroll
    for (int i = 0; i < 2; ++i) {
      int idx = tid + 256 * i;
      int row = idx >> 4, c4 = idx & 15;
      int byte = row * 128 + ((c4 * 8) ^ ((row & 7) << 4));
      float4 v = areg[i];
      short4v h;
      h[0] = f2h(v.x); h[1] = f2h(v.y); h[2] = f2h(v.z); h[3] = f2h(v.w);
      *(short4v*)((char*)Ax[p] + byte) = h;
    }
  };
  auto compute = [&](int p) {
#pragma unroll
    for (int kc = 0; kc < 2; ++kc) {
      const int arow = wr * 16 + c;
      f16x8 a = *(const f16x8*)((const char*)Ax[p] + arow * 128 +
                                ((kc * 64 + (g << 4)) ^ ((arow & 7) << 4)));
#pragma unroll
      for (int nt = 0; nt < 6; ++nt) {
        const int brow = wc * 96 + nt * 16 + c;
        f16x8 b = *(const f16x8*)((const char*)Bw[p] + brow * 128 +
                                  ((kc * 64 + (g << 4)) ^ ((brow & 7) << 4)));
        acc[nt] = __builtin_amdgcn_mfma_f32_16x16x32_f16(a, b, acc[nt], 0, 0, 0);
      }
    }
  };

  stage_B(0, 0);
  load_A(0);
  write_A(0);
  __syncthreads();
#pragma unroll 1
  for (int kt = 0; kt < 16; ++kt) {
    const int p = kt & 1;
    if (kt < 15) { stage_B(kt + 1, p ^ 1); load_A(kt + 1); }
    compute(p);
    if (kt < 15) write_A(p ^ 1);
    __syncthreads();
  }

  float bv[6];
#pragma unroll
  for (int nt = 0; nt < 6; ++nt) bv[nt] = bias[wc * 96 + nt * 16 + c];

  short* VTl = (short*)Ax[0];
  float knorm[4] = {0.f, 0.f, 0.f, 0.f};
#pragma unroll
  for (int nt = 0; nt < 6; ++nt) {
#pragma unroll
    for (int i = 0; i < 4; ++i) {
      int n = wc * 96 + nt * 16 + c;
      int lrow = wr * 16 + (g << 2) + i;
      float v = acc[nt][i] + bv[nt];
      size_t tok = ((size_t)batch << 11) | (size_t)(t0 + lrow);
      if (n < 64) {
        Kb[tok * HD + n] = f2h(v);
        knorm[i] += v * v;
      } else if (n < 128) {
        Qb[tok * HD + (n - 64)] = f2h(v);
      } else {
        int h = n - 128;
        int byte = h * 64 + ((lrow * 2) ^ ((h & 3) << 4));
        *(short*)((char*)VTl + byte) = f2h(v);
      }
    }
  }
  if (wc == 0) {
#pragma unroll
    for (int d = 1; d < 16; d <<= 1)
#pragma unroll
      for (int i = 0; i < 4; ++i) knorm[i] += __shfl_xor(knorm[i], d);
    float mx = fmaxf(fmaxf(knorm[0], knorm[1]), fmaxf(knorm[2], knorm[3]));
    if (c == 0) atomicMax((int*)(kmax2 + batch), __float_as_int(mx));
  }
  __syncthreads();
  {
    int h = tid >> 2, ch = tid & 3;
    short8 v = *(const short8*)((const char*)VTl + h * 64 +
                                ((ch * 16) ^ ((h & 3) << 4)));
    *(short8*)(Vt + (((size_t)(batch * HD + h)) << 11) + (size_t)t0 + ch * 8) = v;
  }
}

// ---- attention: fixed 4-tile chunks, no LDS staging, no loop barriers.
// Swapped QK^T (S^T), packed P via wave-private LDS. Last chunk block combines.
#define PPITCH 136
__launch_bounds__(256)
__global__ void attn_part(const short* __restrict__ Kb, const short* __restrict__ Qb,
                          const short* __restrict__ Vt, const float* __restrict__ kmax2,
                          float* __restrict__ Opart, float* __restrict__ Lpart,
                          int* __restrict__ cnt, float* __restrict__ out) {
  __shared__ char Pl[4][16 * PPITCH];   // per-wave P buffer [q=c][s packed f16]
  __shared__ int flag;

  const int tid = threadIdx.x, lane = tid & 63, wave = tid >> 6;
  const int g = lane >> 4, c = lane & 15;
  const int bid = blockIdx.x;
  const int b = bid >> 8;
  const int qtx = (bid >> 3) & 31;
  const int ch = bid & 7;
  const int qt = 31 - qtx;               // longest-first
  const int nkv = qt + 1;
  const int nch = (nkv + 3) >> 2;
  if (ch >= nch) return;
  const int ks = ch * 4, ke = min(ks + 4, nkv);
  const int q0 = qt * 64;
  const int qg = q0 + wave * 16 + c;     // this lane's q-row (column of S^T)
  const float c2 = 0.125f * 1.44269504088896340736f;

  // Q fragments (B-operand: row=c=q, k-slice kc*32+g*8)
  f16x8 qa[2];
  {
    size_t base = ((size_t)b * NT + (size_t)qg) * HD + (g << 3);
    qa[0] = *(const f16x8*)(Qb + base);
    qa[1] = *(const f16x8*)(Qb + base + 32);
  }
  // fixed per-column max bound m2 = |q_row(c)| * KMAX * c2
  float m2;
  {
    float qn = 0.f;
#pragma unroll
    for (int kc = 0; kc < 2; ++kc)
#pragma unroll
      for (int j = 0; j < 8; ++j) {
        float qv = (float)qa[kc][j];
        qn += qv * qv;
      }
    qn += __shfl_xor(qn, 16);
    qn += __shfl_xor(qn, 32);
    m2 = sqrtf(qn) * sqrtf(kmax2[b]) * c2;
  }

  f32x4 o[4];
#pragma unroll
  for (int nt = 0; nt < 4; ++nt) o[nt] = (f32x4){0.f, 0.f, 0.f, 0.f};
  float l_r = 0.f;

  const short* kbp = Kb + ((size_t)b * NT) * HD;
  const short* vbp = Vt + (((size_t)b * HD) << 11);
  char* pw = Pl[wave];

#pragma unroll 1
  for (int t = ks; t < ke; ++t) {
    const int s0 = t * 64;
    // K fragments (A-operand: row=c=k-row within st tile, k-slice kc*32+g*8)
    f16x8 kfr[4][2];
#pragma unroll
    for (int st = 0; st < 4; ++st) {
      size_t rb = (size_t)(s0 + st * 16 + c) * HD + (g << 3);
      kfr[st][0] = *(const f16x8*)(kbp + rb);
      kfr[st][1] = *(const f16x8*)(kbp + rb + 32);
    }
    // S^T = K Q^T : D[row=s_local][col=q]
    f32x4 s[4];
#pragma unroll
    for (int st = 0; st < 4; ++st) s[st] = (f32x4){0.f, 0.f, 0.f, 0.f};
#pragma unroll
    for (int kc = 0; kc < 2; ++kc)
#pragma unroll
      for (int st = 0; st < 4; ++st)
        s[st] = __builtin_amdgcn_mfma_f32_16x16x32_f16(kfr[st][kc], qa[kc], s[st], 0, 0, 0);

    // P = exp2(S*c2 - m2), mask if s>q on diagonal tile; pack pairs, store b64
    const bool diag = (t == qt);
#pragma unroll
    for (int st = 0; st < 4; ++st) {
      float pv[4];
#pragma unroll
      for (int i = 0; i < 4; ++i) {
        int sg = s0 + st * 16 + (g << 2) + i;
        float p = __builtin_amdgcn_exp2f(s[st][i] * c2 - m2);
        pv[i] = (diag && sg > qg) ? 0.f : p;
      }
      l_r += (pv[0] + pv[1]) + (pv[2] + pv[3]);
      uint2 w;
      w.x = pk2h(pv[0], pv[1]);
      w.y = pk2h(pv[2], pv[3]);
      *(uint2*)(pw + c * PPITCH + st * 32 + g * 8) = w;
    }

    // O += P V : A = P rows q (read back), B = V^T rows h
#pragma unroll
    for (int kc = 0; kc < 2; ++kc) {
      uint2 h0 = *(const uint2*)(pw + c * PPITCH + kc * 64 + g * 16);
      uint2 h1 = *(const uint2*)(pw + c * PPITCH + kc * 64 + g * 16 + 8);
      f16x8 pa;
      *(uint2*)&pa = h0;
      *((uint2*)&pa + 1) = h1;
#pragma unroll
      for (int nt = 0; nt < 4; ++nt) {
        f16x8 vv = *(const f16x8*)(vbp + (((size_t)(nt * 16 + c)) << 11) +
                                   s0 + kc * 32 + (g << 3));
        o[nt] = __builtin_amdgcn_mfma_f32_16x16x32_f16(pa, vv, o[nt], 0, 0, 0);
      }
    }
  }

  // finish l (sum the 4 g-partials per column)
  l_r += __shfl_xor(l_r, 16);
  l_r += __shfl_xor(l_r, 32);

  // write partials
  const int slot = ((b * 32 + qt) << 3) + ch;
  float* ob = Opart + (size_t)slot * 4096 + (size_t)(wave * 16) * 64;
#pragma unroll
  for (int i = 0; i < 4; ++i) {
    int r = (g << 2) + i;
#pragma unroll
    for (int nt = 0; nt < 4; ++nt) ob[r * 64 + nt * 16 + c] = o[nt][i];
  }
  if (g == 0) Lpart[slot * 64 + wave * 16 + c] = l_r;

  // last-arriving chunk block combines
  __syncthreads();
  if (tid == 0) {
    __threadfence();
    int old = atomicAdd(&cnt[b * 32 + qt], 1);
    flag = (old == nch - 1) ? 1 : 0;
  }
  __syncthreads();
  if (!flag) return;
  __threadfence();

  const int base = (b * 32 + qt) << 3;
  f32x4 acc[4];
  float ls[4];
#pragma unroll
  for (int j = 0; j < 4; ++j) { acc[j] = (f32x4){0.f, 0.f, 0.f, 0.f}; ls[j] = 0.f; }
#pragma unroll 1
  for (int c2i = 0; c2i < nch; ++c2i) {
    const float* op = Opart + (size_t)(base + c2i) * 4096;
    const float* lp = Lpart + (base + c2i) * 64;
#pragma unroll
    for (int j = 0; j < 4; ++j) {
      int row = (tid >> 4) + 16 * j;
      acc[j] += *(const f32x4*)(op + row * 64 + (tid & 15) * 4);
      ls[j] += lp[row];
    }
  }
  float* outb = out + ((size_t)b * NT + (size_t)q0) * HD;
#pragma unroll
  for (int j = 0; j < 4; ++j) {
    int row = (tid >> 4) + 16 * j;
    float inv = 1.0f / ls[j];
    f32x4 v = acc[j];
    v[0] *= inv; v[1] *= inv; v[2] *= inv; v[3] *= inv;
    *(f32x4*)(outb + row * 64 + (tid & 15) * 4) = v;
  }
}

extern "C" void kernel_launch(void* const* d_in, const int* in_sizes, int n_in,
                              void* d_out, int out_size, void* d_ws, size_t ws_size,
                              hipStream_t stream) {
  const float* x = (const float*)d_in[0];
  const float* W = (const float*)d_in[1];
  const float* bias = (const float*)d_in[2];
  float* out = (float*)d_out;

  char* ws = (char*)d_ws;
  float* kmax2 = (float*)ws;                       // 8 f32
  int* cnt = (int*)(ws + 256);                     // 256 int
  short* Wt = (short*)(ws + 2048);                 // [192][1024] f16
  short* Kb = Wt + (size_t)N3 * NC;                // [8][2048][64] f16
  short* Qb = Kb + (size_t)NB * NT * HD;           // [8][2048][64] f16
  short* Vt = Qb + (size_t)NB * NT * HD;           // [8][64][2048] f16
  float* Opart = (float*)(Vt + (size_t)NB * NT * HD);   // [2048][64][64] f32
  float* Lpart = Opart + (size_t)2048 * 4096;           // [2048][64] f32

  prep_w<<<64, 256, 0, stream>>>(W, Wt, kmax2, cnt);
  qkv_proj<<<512, 256, 0, stream>>>(x, Wt, bias, Kb, Qb, Vt, kmax2);
  attn_part<<<NB * 32 * 8, 256, 0, stream>>>(Kb, Qb, Vt, kmax2, Opart, Lpart, cnt, out);
}

// Round 6
// 185.417 us; speedup vs baseline: 2.3742x; 2.3742x over previous
//
#include <hip/hip_runtime.h>

#define NB 8
#define NT 2048
#define NC 1024
#define HD 64
#define N3 192

typedef float f32x4 __attribute__((ext_vector_type(4)));
typedef _Float16 f16x8 __attribute__((ext_vector_type(8)));
typedef short short8 __attribute__((ext_vector_type(8)));
typedef short short4v __attribute__((ext_vector_type(4)));

static __device__ __forceinline__ short f2h(float f) {
  _Float16 h = (_Float16)f;
  return __builtin_bit_cast(short, h);
}
static __device__ __forceinline__ unsigned pk2h(float a, float b) {
  unsigned lo = (unsigned short)f2h(a);
  unsigned hi = (unsigned short)f2h(b);
  return lo | (hi << 16);
}

typedef __attribute__((address_space(1))) const void* gptr1;
typedef __attribute__((address_space(3))) void* sptr3;
static __device__ __forceinline__ void gload_lds16(const void* g, void* s) {
  __builtin_amdgcn_global_load_lds((gptr1)g, (sptr3)s, 16, 0, 0);
}

// ---- prep: W[1024][192] f32 -> Wt [192][1024] f16 (transposed); zero kmax2 ----
__launch_bounds__(256)
__global__ void prep_w(const float* __restrict__ W, short* __restrict__ Wt,
                       float* __restrict__ kmax2) {
  if (blockIdx.x == 0 && threadIdx.x < 8) kmax2[threadIdx.x] = 0.f;
  const int n = threadIdx.x;
  if (n >= 192) return;
  const int k0 = blockIdx.x * 16;
  short8 v0, v1;
#pragma unroll
  for (int j = 0; j < 8; ++j) v0[j] = f2h(W[(size_t)(k0 + j) * N3 + n]);
#pragma unroll
  for (int j = 0; j < 8; ++j) v1[j] = f2h(W[(size_t)(k0 + 8 + j) * N3 + n]);
  *(short8*)(Wt + (size_t)n * NC + k0) = v0;
  *(short8*)(Wt + (size_t)n * NC + k0 + 8) = v1;
}

// ---- qkv projection: x[16384,1024]f32 @ W + b, fp16 single-term MFMA ----
__launch_bounds__(256, 2)
__global__ void qkv_proj(const float* __restrict__ x, const short* __restrict__ Wt,
                         const float* __restrict__ bias, short* __restrict__ Kb,
                         short* __restrict__ Qb, short* __restrict__ Vt,
                         float* __restrict__ kmax2) {
  __shared__ short Ax[2][32 * 64];    // [buf][m][k] swizzled (4KB each)
  __shared__ short Bw[2][192 * 64];   // [buf][n][k] swizzled (24KB each)

  const int tid = threadIdx.x;
  const int lane = tid & 63;
  const int wave = tid >> 6;
  const int wr = wave >> 1, wc = wave & 1;   // wave tile: 16 m-rows x 96 n-cols
  const int r0 = blockIdx.x * 32;
  const int batch = r0 >> 11;
  const int t0 = r0 & (NT - 1);
  const int g = lane >> 4, c = lane & 15;

  const int bsub = lane >> 3;
  const size_t bgoff = (size_t)bsub * (NC * 2) + (size_t)((lane & 7) ^ bsub) * 16;

  f32x4 acc[6];
#pragma unroll
  for (int nt = 0; nt < 6; ++nt) acc[nt] = (f32x4){0.f, 0.f, 0.f, 0.f};

  float4 areg[2];

  auto stage_B = [&](int kt, int p) {
    const char* src = (const char*)Wt + (size_t)(wave * 48) * (NC * 2) +
                      (size_t)kt * 128 + bgoff;
    char* dst = (char*)Bw[p] + wave * 48 * 128;
#pragma unroll
    for (int j = 0; j < 6; ++j)
      gload_lds16(src + (size_t)(j * 8) * (NC * 2), dst + j * 8 * 128);
  };
  auto load_A = [&](int kt) {
    const float* xp = x + (size_t)r0 * NC + kt * 64;
#pragma unroll
    for (int i = 0; i < 2; ++i) {
      int idx = tid + 256 * i;
      int row = idx >> 4, c4 = idx & 15;
      areg[i] = *(const float4*)(xp + (size_t)row * NC + c4 * 4);
    }
  };
  auto write_A = [&](int p) {
#pragma unroll
    for (int i = 0; i < 2; ++i) {
      int idx = tid + 256 * i;
      int row = idx >> 4, c4 = idx & 15;
      int byte = row * 128 + ((c4 * 8) ^ ((row & 7) << 4));
      float4 v = areg[i];
      short4v h;
      h[0] = f2h(v.x); h[1] = f2h(v.y); h[2] = f2h(v.z); h[3] = f2h(v.w);
      *(short4v*)((char*)Ax[p] + byte) = h;
    }
  };
  auto compute = [&](int p) {
#pragma unroll
    for (int kc = 0; kc < 2; ++kc) {
      const int arow = wr * 16 + c;
      f16x8 a = *(const f16x8*)((const char*)Ax[p] + arow * 128 +
                                ((kc * 64 + (g << 4)) ^ ((arow & 7) << 4)));
#pragma unroll
      for (int nt = 0; nt < 6; ++nt) {
        const int brow = wc * 96 + nt * 16 + c;
        f16x8 b = *(const f16x8*)((const char*)Bw[p] + brow * 128 +
                                  ((kc * 64 + (g << 4)) ^ ((brow & 7) << 4)));
        acc[nt] = __builtin_amdgcn_mfma_f32_16x16x32_f16(a, b, acc[nt], 0, 0, 0);
      }
    }
  };

  stage_B(0, 0);
  load_A(0);
  write_A(0);
  __syncthreads();
#pragma unroll 1
  for (int kt = 0; kt < 16; ++kt) {
    const int p = kt & 1;
    if (kt < 15) { stage_B(kt + 1, p ^ 1); load_A(kt + 1); }
    compute(p);
    if (kt < 15) write_A(p ^ 1);
    __syncthreads();
  }

  float bv[6];
#pragma unroll
  for (int nt = 0; nt < 6; ++nt) bv[nt] = bias[wc * 96 + nt * 16 + c];

  short* VTl = (short*)Ax[0];
  float knorm[4] = {0.f, 0.f, 0.f, 0.f};
#pragma unroll
  for (int nt = 0; nt < 6; ++nt) {
#pragma unroll
    for (int i = 0; i < 4; ++i) {
      int n = wc * 96 + nt * 16 + c;
      int lrow = wr * 16 + (g << 2) + i;
      float v = acc[nt][i] + bv[nt];
      size_t tok = ((size_t)batch << 11) | (size_t)(t0 + lrow);
      if (n < 64) {
        Kb[tok * HD + n] = f2h(v);
        knorm[i] += v * v;
      } else if (n < 128) {
        Qb[tok * HD + (n - 64)] = f2h(v);
      } else {
        int h = n - 128;
        int byte = h * 64 + ((lrow * 2) ^ ((h & 3) << 4));
        *(short*)((char*)VTl + byte) = f2h(v);
      }
    }
  }
  if (wc == 0) {
#pragma unroll
    for (int d = 1; d < 16; d <<= 1)
#pragma unroll
      for (int i = 0; i < 4; ++i) knorm[i] += __shfl_xor(knorm[i], d);
    float mx = fmaxf(fmaxf(knorm[0], knorm[1]), fmaxf(knorm[2], knorm[3]));
    if (c == 0) atomicMax((int*)(kmax2 + batch), __float_as_int(mx));
  }
  __syncthreads();
  {
    int h = tid >> 2, ch = tid & 3;
    short8 v = *(const short8*)((const char*)VTl + h * 64 +
                                ((ch * 16) ^ ((h & 3) << 4)));
    *(short8*)(Vt + (((size_t)(batch * HD + h)) << 11) + (size_t)t0 + ch * 8) = v;
  }
}

// ---- attention partials: fixed 4-tile chunks, no LDS staging, no loop barriers,
// no fences. Swapped QK^T (S^T), packed P via wave-private LDS.
#define PPITCH 136
__launch_bounds__(256)
__global__ void attn_part(const short* __restrict__ Kb, const short* __restrict__ Qb,
                          const short* __restrict__ Vt, const float* __restrict__ kmax2,
                          float* __restrict__ Opart, float* __restrict__ Lpart) {
  __shared__ char Pl[4][16 * PPITCH];   // per-wave P buffer [q=c][s packed f16]

  const int tid = threadIdx.x, lane = tid & 63, wave = tid >> 6;
  const int g = lane >> 4, c = lane & 15;
  const int bid = blockIdx.x;
  const int b = bid >> 8;
  const int qtx = (bid >> 3) & 31;
  const int ch = bid & 7;
  const int qt = 31 - qtx;               // longest-first
  const int nkv = qt + 1;
  const int nch = (nkv + 3) >> 2;
  if (ch >= nch) return;
  const int ks = ch * 4, ke = min(ks + 4, nkv);
  const int q0 = qt * 64;
  const int qg = q0 + wave * 16 + c;     // this lane's q-row (column of S^T)
  const float c2 = 0.125f * 1.44269504088896340736f;

  // Q fragments (B-operand: row=c=q, k-slice kc*32+g*8)
  f16x8 qa[2];
  {
    size_t base = ((size_t)b * NT + (size_t)qg) * HD + (g << 3);
    qa[0] = *(const f16x8*)(Qb + base);
    qa[1] = *(const f16x8*)(Qb + base + 32);
  }
  // fixed per-column max bound m2 = |q_row(c)| * KMAX * c2
  float m2;
  {
    float qn = 0.f;
#pragma unroll
    for (int kc = 0; kc < 2; ++kc)
#pragma unroll
      for (int j = 0; j < 8; ++j) {
        float qv = (float)qa[kc][j];
        qn += qv * qv;
      }
    qn += __shfl_xor(qn, 16);
    qn += __shfl_xor(qn, 32);
    m2 = sqrtf(qn) * sqrtf(kmax2[b]) * c2;
  }

  f32x4 o[4];
#pragma unroll
  for (int nt = 0; nt < 4; ++nt) o[nt] = (f32x4){0.f, 0.f, 0.f, 0.f};
  float l_r = 0.f;

  const short* kbp = Kb + ((size_t)b * NT) * HD;
  const short* vbp = Vt + (((size_t)b * HD) << 11);
  char* pw = Pl[wave];

#pragma unroll 1
  for (int t = ks; t < ke; ++t) {
    const int s0 = t * 64;
    // K fragments (A-operand: row=c within st tile, k-slice kc*32+g*8)
    f16x8 kfr[4][2];
#pragma unroll
    for (int st = 0; st < 4; ++st) {
      size_t rb = (size_t)(s0 + st * 16 + c) * HD + (g << 3);
      kfr[st][0] = *(const f16x8*)(kbp + rb);
      kfr[st][1] = *(const f16x8*)(kbp + rb + 32);
    }
    // S^T = K Q^T : D[row=s_local][col=q]
    f32x4 s[4];
#pragma unroll
    for (int st = 0; st < 4; ++st) s[st] = (f32x4){0.f, 0.f, 0.f, 0.f};
#pragma unroll
    for (int kc = 0; kc < 2; ++kc)
#pragma unroll
      for (int st = 0; st < 4; ++st)
        s[st] = __builtin_amdgcn_mfma_f32_16x16x32_f16(kfr[st][kc], qa[kc], s[st], 0, 0, 0);

    // P = exp2(S*c2 - m2), mask if s>q on diagonal tile; pack pairs, store b64
    const bool diag = (t == qt);
#pragma unroll
    for (int st = 0; st < 4; ++st) {
      float pv[4];
#pragma unroll
      for (int i = 0; i < 4; ++i) {
        int sg = s0 + st * 16 + (g << 2) + i;
        float p = __builtin_amdgcn_exp2f(s[st][i] * c2 - m2);
        pv[i] = (diag && sg > qg) ? 0.f : p;
      }
      l_r += (pv[0] + pv[1]) + (pv[2] + pv[3]);
      uint2 w;
      w.x = pk2h(pv[0], pv[1]);
      w.y = pk2h(pv[2], pv[3]);
      *(uint2*)(pw + c * PPITCH + st * 32 + g * 8) = w;
    }

    // O += P V : A = P rows q (read back), B = V^T rows h
#pragma unroll
    for (int kc = 0; kc < 2; ++kc) {
      uint2 h0 = *(const uint2*)(pw + c * PPITCH + kc * 64 + g * 16);
      uint2 h1 = *(const uint2*)(pw + c * PPITCH + kc * 64 + g * 16 + 8);
      f16x8 pa;
      *(uint2*)&pa = h0;
      *((uint2*)&pa + 1) = h1;
#pragma unroll
      for (int nt = 0; nt < 4; ++nt) {
        f16x8 vv = *(const f16x8*)(vbp + (((size_t)(nt * 16 + c)) << 11) +
                                   s0 + kc * 32 + (g << 3));
        o[nt] = __builtin_amdgcn_mfma_f32_16x16x32_f16(pa, vv, o[nt], 0, 0, 0);
      }
    }
  }

  // finish l (sum the 4 g-partials per column)
  l_r += __shfl_xor(l_r, 16);
  l_r += __shfl_xor(l_r, 32);

  // write partials (D layout: col=c within 16-col tile, row=g*4+i)
  const int slot = ((b * 32 + qt) << 3) + ch;
  float* ob = Opart + (size_t)slot * 4096 + (size_t)(wave * 16) * 64;
#pragma unroll
  for (int i = 0; i < 4; ++i) {
    int r = (g << 2) + i;
#pragma unroll
    for (int nt = 0; nt < 4; ++nt) ob[r * 64 + nt * 16 + c] = o[nt][i];
  }
  if (g == 0) Lpart[slot * 64 + wave * 16 + c] = l_r;
}

// ---- combine: sum live chunk partials, normalize, write out ----
__launch_bounds__(256)
__global__ void attn_comb(const float* __restrict__ Opart, const float* __restrict__ Lpart,
                          float* __restrict__ out) {
  const int qt = blockIdx.x & 31;
  const int b = blockIdx.x >> 5;
  const int nch = (qt + 4) >> 2;        // ceil((qt+1)/4)
  const int t = threadIdx.x;
  const int base = (b * 32 + qt) << 3;

  f32x4 acc[4];
  float ls[4];
#pragma unroll
  for (int j = 0; j < 4; ++j) { acc[j] = (f32x4){0.f, 0.f, 0.f, 0.f}; ls[j] = 0.f; }

#pragma unroll 1
  for (int ci = 0; ci < nch; ++ci) {
    const float* op = Opart + (size_t)(base + ci) * 4096;
    const float* lp = Lpart + (base + ci) * 64;
#pragma unroll
    for (int j = 0; j < 4; ++j) {
      int row = (t >> 4) + 16 * j;
      acc[j] += *(const f32x4*)(op + row * 64 + (t & 15) * 4);
      ls[j] += lp[row];
    }
  }
  float* ob = out + ((size_t)b * NT + (size_t)(qt * 64)) * HD;
#pragma unroll
  for (int j = 0; j < 4; ++j) {
    int row = (t >> 4) + 16 * j;
    float inv = 1.0f / ls[j];
    f32x4 v = acc[j];
    v[0] *= inv; v[1] *= inv; v[2] *= inv; v[3] *= inv;
    *(f32x4*)(ob + row * 64 + (t & 15) * 4) = v;
  }
}

extern "C" void kernel_launch(void* const* d_in, const int* in_sizes, int n_in,
                              void* d_out, int out_size, void* d_ws, size_t ws_size,
                              hipStream_t stream) {
  const float* x = (const float*)d_in[0];
  const float* W = (const float*)d_in[1];
  const float* bias = (const float*)d_in[2];
  float* out = (float*)d_out;

  char* ws = (char*)d_ws;
  float* kmax2 = (float*)ws;                       // 8 f32
  short* Wt = (short*)(ws + 2048);                 // [192][1024] f16
  short* Kb = Wt + (size_t)N3 * NC;                // [8][2048][64] f16
  short* Qb = Kb + (size_t)NB * NT * HD;           // [8][2048][64] f16
  short* Vt = Qb + (size_t)NB * NT * HD;           // [8][64][2048] f16
  float* Opart = (float*)(Vt + (size_t)NB * NT * HD);   // [2048][64][64] f32
  float* Lpart = Opart + (size_t)2048 * 4096;           // [2048][64] f32

  prep_w<<<64, 256, 0, stream>>>(W, Wt, kmax2);
  qkv_proj<<<512, 256, 0, stream>>>(x, Wt, bias, Kb, Qb, Vt, kmax2);
  attn_part<<<NB * 32 * 8, 256, 0, stream>>>(Kb, Qb, Vt, kmax2, Opart, Lpart);
  attn_comb<<<NB * 32, 256, 0, stream>>>(Opart, Lpart, out);
}

// Round 7
// 173.080 us; speedup vs baseline: 2.5434x; 1.0713x over previous
//
#include <hip/hip_runtime.h>

#define NB 8
#define NT 2048
#define NC 1024
#define HD 64
#define N3 192

typedef float f32x4 __attribute__((ext_vector_type(4)));
typedef _Float16 f16x8 __attribute__((ext_vector_type(8)));
typedef short short8 __attribute__((ext_vector_type(8)));
typedef short short4v __attribute__((ext_vector_type(4)));

static __device__ __forceinline__ short f2h(float f) {
  _Float16 h = (_Float16)f;
  return __builtin_bit_cast(short, h);
}
static __device__ __forceinline__ unsigned pk2h(float a, float b) {
  unsigned lo = (unsigned short)f2h(a);
  unsigned hi = (unsigned short)f2h(b);
  return lo | (hi << 16);
}

typedef __attribute__((address_space(1))) const void* gptr1;
typedef __attribute__((address_space(3))) void* sptr3;
static __device__ __forceinline__ void gload_lds16(const void* g, void* s) {
  __builtin_amdgcn_global_load_lds((gptr1)g, (sptr3)s, 16, 0, 0);
}

// ---- prep: W[1024][192] f32 -> Wt [192][1024] f16 (transposed); zero kmax2 ----
__launch_bounds__(256)
__global__ void prep_w(const float* __restrict__ W, short* __restrict__ Wt,
                       float* __restrict__ kmax2) {
  if (blockIdx.x == 0 && threadIdx.x < 8) kmax2[threadIdx.x] = 0.f;
  const int n = threadIdx.x;
  if (n >= 192) return;
  const int k0 = blockIdx.x * 16;
  short8 v0, v1;
#pragma unroll
  for (int j = 0; j < 8; ++j) v0[j] = f2h(W[(size_t)(k0 + j) * N3 + n]);
#pragma unroll
  for (int j = 0; j < 8; ++j) v1[j] = f2h(W[(size_t)(k0 + 8 + j) * N3 + n]);
  *(short8*)(Wt + (size_t)n * NC + k0) = v0;
  *(short8*)(Wt + (size_t)n * NC + k0 + 8) = v1;
}

// ---- qkv projection: x[16384,1024]f32 @ W + b, fp16 single-term MFMA ----
__launch_bounds__(256, 2)
__global__ void qkv_proj(const float* __restrict__ x, const short* __restrict__ Wt,
                         const float* __restrict__ bias, short* __restrict__ Kb,
                         short* __restrict__ Qb, short* __restrict__ Vt,
                         float* __restrict__ kmax2) {
  __shared__ short Ax[2][32 * 64];    // [buf][m][k] swizzled (4KB each)
  __shared__ short Bw[2][192 * 64];   // [buf][n][k] swizzled (24KB each)

  const int tid = threadIdx.x;
  const int lane = tid & 63;
  const int wave = tid >> 6;
  const int wr = wave >> 1, wc = wave & 1;   // wave tile: 16 m-rows x 96 n-cols
  const int r0 = blockIdx.x * 32;
  const int batch = r0 >> 11;
  const int t0 = r0 & (NT - 1);
  const int g = lane >> 4, c = lane & 15;

  const int bsub = lane >> 3;
  const size_t bgoff = (size_t)bsub * (NC * 2) + (size_t)((lane & 7) ^ bsub) * 16;

  f32x4 acc[6];
#pragma unroll
  for (int nt = 0; nt < 6; ++nt) acc[nt] = (f32x4){0.f, 0.f, 0.f, 0.f};

  float4 areg[2];

  auto stage_B = [&](int kt, int p) {
    const char* src = (const char*)Wt + (size_t)(wave * 48) * (NC * 2) +
                      (size_t)kt * 128 + bgoff;
    char* dst = (char*)Bw[p] + wave * 48 * 128;
#pragma unroll
    for (int j = 0; j < 6; ++j)
      gload_lds16(src + (size_t)(j * 8) * (NC * 2), dst + j * 8 * 128);
  };
  auto load_A = [&](int kt) {
    const float* xp = x + (size_t)r0 * NC + kt * 64;
#pragma unroll
    for (int i = 0; i < 2; ++i) {
      int idx = tid + 256 * i;
      int row = idx >> 4, c4 = idx & 15;
      areg[i] = *(const float4*)(xp + (size_t)row * NC + c4 * 4);
    }
  };
  auto write_A = [&](int p) {
#pragma unroll
    for (int i = 0; i < 2; ++i) {
      int idx = tid + 256 * i;
      int row = idx >> 4, c4 = idx & 15;
      int byte = row * 128 + ((c4 * 8) ^ ((row & 7) << 4));
      float4 v = areg[i];
      short4v h;
      h[0] = f2h(v.x); h[1] = f2h(v.y); h[2] = f2h(v.z); h[3] = f2h(v.w);
      *(short4v*)((char*)Ax[p] + byte) = h;
    }
  };
  auto compute = [&](int p) {
#pragma unroll
    for (int kc = 0; kc < 2; ++kc) {
      const int arow = wr * 16 + c;
      f16x8 a = *(const f16x8*)((const char*)Ax[p] + arow * 128 +
                                ((kc * 64 + (g << 4)) ^ ((arow & 7) << 4)));
#pragma unroll
      for (int nt = 0; nt < 6; ++nt) {
        const int brow = wc * 96 + nt * 16 + c;
        f16x8 b = *(const f16x8*)((const char*)Bw[p] + brow * 128 +
                                  ((kc * 64 + (g << 4)) ^ ((brow & 7) << 4)));
        acc[nt] = __builtin_amdgcn_mfma_f32_16x16x32_f16(a, b, acc[nt], 0, 0, 0);
      }
    }
  };

  stage_B(0, 0);
  load_A(0);
  write_A(0);
  __syncthreads();
#pragma unroll 1
  for (int kt = 0; kt < 16; ++kt) {
    const int p = kt & 1;
    if (kt < 15) { stage_B(kt + 1, p ^ 1); load_A(kt + 1); }
    compute(p);
    if (kt < 15) write_A(p ^ 1);
    __syncthreads();
  }

  float bv[6];
#pragma unroll
  for (int nt = 0; nt < 6; ++nt) bv[nt] = bias[wc * 96 + nt * 16 + c];

  short* VTl = (short*)Ax[0];
  float knorm[4] = {0.f, 0.f, 0.f, 0.f};
#pragma unroll
  for (int nt = 0; nt < 6; ++nt) {
#pragma unroll
    for (int i = 0; i < 4; ++i) {
      int n = wc * 96 + nt * 16 + c;
      int lrow = wr * 16 + (g << 2) + i;
      float v = acc[nt][i] + bv[nt];
      size_t tok = ((size_t)batch << 11) | (size_t)(t0 + lrow);
      if (n < 64) {
        Kb[tok * HD + n] = f2h(v);
        knorm[i] += v * v;
      } else if (n < 128) {
        Qb[tok * HD + (n - 64)] = f2h(v);
      } else {
        int h = n - 128;
        int byte = h * 64 + ((lrow * 2) ^ ((h & 3) << 4));
        *(short*)((char*)VTl + byte) = f2h(v);
      }
    }
  }
  if (wc == 0) {
#pragma unroll
    for (int d = 1; d < 16; d <<= 1)
#pragma unroll
      for (int i = 0; i < 4; ++i) knorm[i] += __shfl_xor(knorm[i], d);
    float mx = fmaxf(fmaxf(knorm[0], knorm[1]), fmaxf(knorm[2], knorm[3]));
    if (c == 0) atomicMax((int*)(kmax2 + batch), __float_as_int(mx));
  }
  __syncthreads();
  {
    int h = tid >> 2, ch = tid & 3;
    short8 v = *(const short8*)((const char*)VTl + h * 64 +
                                ((ch * 16) ^ ((h & 3) << 4)));
    *(short8*)(Vt + (((size_t)(batch * HD + h)) << 11) + (size_t)t0 + ch * 8) = v;
  }
}

// ---- attention: one block per (batch, 64-row q-tile), full causal sweep,
// two-deep register ping-pong pipeline (prefetch K/V(t+1) under compute(t)),
// swapped QK^T, packed P via wave-private LDS, in-kernel normalize. ----
#define PPITCH 136
__launch_bounds__(256)
__global__ void attn(const short* __restrict__ Kb, const short* __restrict__ Qb,
                     const short* __restrict__ Vt, const float* __restrict__ kmax2,
                     float* __restrict__ out) {
  __shared__ char Pl[4][16 * PPITCH];   // per-wave P buffer [q=c][s packed f16]

  const int tid = threadIdx.x, lane = tid & 63, wave = tid >> 6;
  const int g = lane >> 4, c = lane & 15;
  const int qt = blockIdx.x & 31;
  const int b = blockIdx.x >> 5;
  const int nkv = qt + 1;
  const int q0 = qt * 64;
  const int qg = q0 + wave * 16 + c;     // this lane's q-row (column of S^T)
  const float c2 = 0.125f * 1.44269504088896340736f;

  // Q fragments (B-operand: row=c=q, k-slice kc*32+g*8)
  f16x8 qa[2];
  {
    size_t base = ((size_t)b * NT + (size_t)qg) * HD + (g << 3);
    qa[0] = *(const f16x8*)(Qb + base);
    qa[1] = *(const f16x8*)(Qb + base + 32);
  }
  // fixed per-column max bound m2 = |q_row(c)| * KMAX * c2
  float m2;
  {
    float qn = 0.f;
#pragma unroll
    for (int kc = 0; kc < 2; ++kc)
#pragma unroll
      for (int j = 0; j < 8; ++j) {
        float qv = (float)qa[kc][j];
        qn += qv * qv;
      }
    qn += __shfl_xor(qn, 16);
    qn += __shfl_xor(qn, 32);
    m2 = sqrtf(qn) * sqrtf(kmax2[b]) * c2;
  }

  f32x4 o[4];
#pragma unroll
  for (int nt = 0; nt < 4; ++nt) o[nt] = (f32x4){0.f, 0.f, 0.f, 0.f};
  float l_r = 0.f;

  const short* kbp = Kb + ((size_t)b * NT) * HD;
  const short* vbp = Vt + (((size_t)b * HD) << 11);
  char* pw = Pl[wave];

  f16x8 kA[4][2], vA[4][2], kB[4][2], vB[4][2];

  auto loadKV = [&](f16x8 (&kf)[4][2], f16x8 (&vf)[4][2], int t) {
    const int s0 = t * 64;
#pragma unroll
    for (int st = 0; st < 4; ++st) {
      size_t rb = (size_t)(s0 + st * 16 + c) * HD + (g << 3);
      kf[st][0] = *(const f16x8*)(kbp + rb);
      kf[st][1] = *(const f16x8*)(kbp + rb + 32);
      size_t vb = (((size_t)(st * 16 + c)) << 11) + (size_t)s0 + (g << 3);
      vf[st][0] = *(const f16x8*)(vbp + vb);
      vf[st][1] = *(const f16x8*)(vbp + vb + 32);
    }
  };

  auto step = [&](f16x8 (&kf)[4][2], f16x8 (&vf)[4][2], int t) {
    const int s0 = t * 64;
    // S^T = K Q^T : D[row=s_local][col=q]
    f32x4 s[4];
#pragma unroll
    for (int st = 0; st < 4; ++st) s[st] = (f32x4){0.f, 0.f, 0.f, 0.f};
#pragma unroll
    for (int kc = 0; kc < 2; ++kc)
#pragma unroll
      for (int st = 0; st < 4; ++st)
        s[st] = __builtin_amdgcn_mfma_f32_16x16x32_f16(kf[st][kc], qa[kc], s[st], 0, 0, 0);

    // P = exp2(S*c2 - m2), mask if s>q on diagonal tile; pack pairs, store b64
    const bool diag = (t == qt);
#pragma unroll
    for (int st = 0; st < 4; ++st) {
      float pv[4];
#pragma unroll
      for (int i = 0; i < 4; ++i) {
        int sg = s0 + st * 16 + (g << 2) + i;
        float p = __builtin_amdgcn_exp2f(s[st][i] * c2 - m2);
        pv[i] = (diag && sg > qg) ? 0.f : p;
      }
      l_r += (pv[0] + pv[1]) + (pv[2] + pv[3]);
      uint2 w;
      w.x = pk2h(pv[0], pv[1]);
      w.y = pk2h(pv[2], pv[3]);
      *(uint2*)(pw + c * PPITCH + st * 32 + g * 8) = w;
    }

    // O += P V : A = P rows q (read back), B = V^T rows h
#pragma unroll
    for (int kc = 0; kc < 2; ++kc) {
      uint2 h0 = *(const uint2*)(pw + c * PPITCH + kc * 64 + g * 16);
      uint2 h1 = *(const uint2*)(pw + c * PPITCH + kc * 64 + g * 16 + 8);
      f16x8 pa;
      *(uint2*)&pa = h0;
      *((uint2*)&pa + 1) = h1;
#pragma unroll
      for (int nt = 0; nt < 4; ++nt)
        o[nt] = __builtin_amdgcn_mfma_f32_16x16x32_f16(pa, vf[nt][kc], o[nt], 0, 0, 0);
    }
  };

  // two-deep ping-pong pipeline: prefetch t+1 while computing t
  loadKV(kA, vA, 0);
  int t = 0;
  while (true) {
    if (t + 1 < nkv) loadKV(kB, vB, t + 1);
    step(kA, vA, t);
    ++t;
    if (t >= nkv) break;
    if (t + 1 < nkv) loadKV(kA, vA, t + 1);
    step(kB, vB, t);
    ++t;
    if (t >= nkv) break;
  }

  // finish l (sum the 4 g-partials per column), normalize, write out
  l_r += __shfl_xor(l_r, 16);
  l_r += __shfl_xor(l_r, 32);
  float* outb = out + ((size_t)b * NT + (size_t)(q0 + wave * 16)) * HD;
#pragma unroll
  for (int i = 0; i < 4; ++i) {
    int r = (g << 2) + i;
    float inv = 1.0f / __shfl(l_r, r);
#pragma unroll
    for (int nt = 0; nt < 4; ++nt)
      outb[(size_t)r * HD + nt * 16 + c] = o[nt][i] * inv;
  }
}

extern "C" void kernel_launch(void* const* d_in, const int* in_sizes, int n_in,
                              void* d_out, int out_size, void* d_ws, size_t ws_size,
                              hipStream_t stream) {
  const float* x = (const float*)d_in[0];
  const float* W = (const float*)d_in[1];
  const float* bias = (const float*)d_in[2];
  float* out = (float*)d_out;

  char* ws = (char*)d_ws;
  float* kmax2 = (float*)ws;                       // 8 f32
  short* Wt = (short*)(ws + 2048);                 // [192][1024] f16
  short* Kb = Wt + (size_t)N3 * NC;                // [8][2048][64] f16
  short* Qb = Kb + (size_t)NB * NT * HD;           // [8][2048][64] f16
  short* Vt = Qb + (size_t)NB * NT * HD;           // [8][64][2048] f16

  prep_w<<<64, 256, 0, stream>>>(W, Wt, kmax2);
  qkv_proj<<<512, 256, 0, stream>>>(x, Wt, bias, Kb, Qb, Vt, kmax2);
  attn<<<NB * 32, 256, 0, stream>>>(Kb, Qb, Vt, kmax2, out);
}

// Round 8
// 151.465 us; speedup vs baseline: 2.9064x; 1.1427x over previous
//
#include <hip/hip_runtime.h>

#define NB 8
#define NT 2048
#define NC 1024
#define HD 64
#define N3 192

typedef float f32x4 __attribute__((ext_vector_type(4)));
typedef _Float16 f16x8 __attribute__((ext_vector_type(8)));
typedef short short8 __attribute__((ext_vector_type(8)));
typedef short short4v __attribute__((ext_vector_type(4)));

static __device__ __forceinline__ short f2h(float f) {
  _Float16 h = (_Float16)f;
  return __builtin_bit_cast(short, h);
}
static __device__ __forceinline__ unsigned pk2h(float a, float b) {
  unsigned lo = (unsigned short)f2h(a);
  unsigned hi = (unsigned short)f2h(b);
  return lo | (hi << 16);
}

typedef __attribute__((address_space(1))) const void* gptr1;
typedef __attribute__((address_space(3))) void* sptr3;
static __device__ __forceinline__ void gload_lds16(const void* g, void* s) {
  __builtin_amdgcn_global_load_lds((gptr1)g, (sptr3)s, 16, 0, 0);
}

// ---- prep: W[1024][192] f32 -> Wt [192][1024] f16 (transposed); zero kmax2 ----
__launch_bounds__(256)
__global__ void prep_w(const float* __restrict__ W, short* __restrict__ Wt,
                       float* __restrict__ kmax2) {
  if (blockIdx.x == 0 && threadIdx.x < 8) kmax2[threadIdx.x] = 0.f;
  const int n = threadIdx.x;
  if (n >= 192) return;
  const int k0 = blockIdx.x * 16;
  short8 v0, v1;
#pragma unroll
  for (int j = 0; j < 8; ++j) v0[j] = f2h(W[(size_t)(k0 + j) * N3 + n]);
#pragma unroll
  for (int j = 0; j < 8; ++j) v1[j] = f2h(W[(size_t)(k0 + 8 + j) * N3 + n]);
  *(short8*)(Wt + (size_t)n * NC + k0) = v0;
  *(short8*)(Wt + (size_t)n * NC + k0 + 8) = v1;
}

// ---- qkv projection: x[16384,1024]f32 @ W + b, fp16 single-term MFMA ----
__launch_bounds__(256, 2)
__global__ void qkv_proj(const float* __restrict__ x, const short* __restrict__ Wt,
                         const float* __restrict__ bias, short* __restrict__ Kb,
                         short* __restrict__ Qb, short* __restrict__ Vt,
                         float* __restrict__ kmax2) {
  __shared__ short Ax[2][32 * 64];    // [buf][m][k] swizzled (4KB each)
  __shared__ short Bw[2][192 * 64];   // [buf][n][k] swizzled (24KB each)

  const int tid = threadIdx.x;
  const int lane = tid & 63;
  const int wave = tid >> 6;
  const int wr = wave >> 1, wc = wave & 1;   // wave tile: 16 m-rows x 96 n-cols
  const int r0 = blockIdx.x * 32;
  const int batch = r0 >> 11;
  const int t0 = r0 & (NT - 1);
  const int g = lane >> 4, c = lane & 15;

  const int bsub = lane >> 3;
  const size_t bgoff = (size_t)bsub * (NC * 2) + (size_t)((lane & 7) ^ bsub) * 16;

  f32x4 acc[6];
#pragma unroll
  for (int nt = 0; nt < 6; ++nt) acc[nt] = (f32x4){0.f, 0.f, 0.f, 0.f};

  float4 areg[2];

  auto stage_B = [&](int kt, int p) {
    const char* src = (const char*)Wt + (size_t)(wave * 48) * (NC * 2) +
                      (size_t)kt * 128 + bgoff;
    char* dst = (char*)Bw[p] + wave * 48 * 128;
#pragma unroll
    for (int j = 0; j < 6; ++j)
      gload_lds16(src + (size_t)(j * 8) * (NC * 2), dst + j * 8 * 128);
  };
  auto load_A = [&](int kt) {
    const float* xp = x + (size_t)r0 * NC + kt * 64;
#pragma unroll
    for (int i = 0; i < 2; ++i) {
      int idx = tid + 256 * i;
      int row = idx >> 4, c4 = idx & 15;
      areg[i] = *(const float4*)(xp + (size_t)row * NC + c4 * 4);
    }
  };
  auto write_A = [&](int p) {
#pragma unroll
    for (int i = 0; i < 2; ++i) {
      int idx = tid + 256 * i;
      int row = idx >> 4, c4 = idx & 15;
      int byte = row * 128 + ((c4 * 8) ^ ((row & 7) << 4));
      float4 v = areg[i];
      short4v h;
      h[0] = f2h(v.x); h[1] = f2h(v.y); h[2] = f2h(v.z); h[3] = f2h(v.w);
      *(short4v*)((char*)Ax[p] + byte) = h;
    }
  };
  auto compute = [&](int p) {
#pragma unroll
    for (int kc = 0; kc < 2; ++kc) {
      const int arow = wr * 16 + c;
      f16x8 a = *(const f16x8*)((const char*)Ax[p] + arow * 128 +
                                ((kc * 64 + (g << 4)) ^ ((arow & 7) << 4)));
#pragma unroll
      for (int nt = 0; nt < 6; ++nt) {
        const int brow = wc * 96 + nt * 16 + c;
        f16x8 b = *(const f16x8*)((const char*)Bw[p] + brow * 128 +
                                  ((kc * 64 + (g << 4)) ^ ((brow & 7) << 4)));
        acc[nt] = __builtin_amdgcn_mfma_f32_16x16x32_f16(a, b, acc[nt], 0, 0, 0);
      }
    }
  };

  stage_B(0, 0);
  load_A(0);
  write_A(0);
  __syncthreads();
#pragma unroll 1
  for (int kt = 0; kt < 16; ++kt) {
    const int p = kt & 1;
    if (kt < 15) { stage_B(kt + 1, p ^ 1); load_A(kt + 1); }
    compute(p);
    if (kt < 15) write_A(p ^ 1);
    __syncthreads();
  }

  float bv[6];
#pragma unroll
  for (int nt = 0; nt < 6; ++nt) bv[nt] = bias[wc * 96 + nt * 16 + c];

  short* VTl = (short*)Ax[0];
  float knorm[4] = {0.f, 0.f, 0.f, 0.f};
#pragma unroll
  for (int nt = 0; nt < 6; ++nt) {
#pragma unroll
    for (int i = 0; i < 4; ++i) {
      int n = wc * 96 + nt * 16 + c;
      int lrow = wr * 16 + (g << 2) + i;
      float v = acc[nt][i] + bv[nt];
      size_t tok = ((size_t)batch << 11) | (size_t)(t0 + lrow);
      if (n < 64) {
        Kb[tok * HD + n] = f2h(v);
        knorm[i] += v * v;
      } else if (n < 128) {
        Qb[tok * HD + (n - 64)] = f2h(v);
      } else {
        int h = n - 128;
        int byte = h * 64 + ((lrow * 2) ^ ((h & 3) << 4));
        *(short*)((char*)VTl + byte) = f2h(v);
      }
    }
  }
  if (wc == 0) {
#pragma unroll
    for (int d = 1; d < 16; d <<= 1)
#pragma unroll
      for (int i = 0; i < 4; ++i) knorm[i] += __shfl_xor(knorm[i], d);
    float mx = fmaxf(fmaxf(knorm[0], knorm[1]), fmaxf(knorm[2], knorm[3]));
    if (c == 0) atomicMax((int*)(kmax2 + batch), __float_as_int(mx));
  }
  __syncthreads();
  {
    int h = tid >> 2, ch = tid & 3;
    short8 v = *(const short8*)((const char*)VTl + h * 64 +
                                ((ch * 16) ^ ((h & 3) << 4)));
    *(short8*)(Vt + (((size_t)(batch * HD + h)) << 11) + (size_t)t0 + ch * 8) = v;
  }
}

// ---- attention: block = (batch, 64-row q-tile); XCD = batch (bid&7).
// K/V double-buffered in LDS via global_load_lds (pre-swizzled src), 2-phase:
// stage(t+1) -> compute(t) -> barrier. Swapped QK^T, packed P, in-kernel norm.
#define PPITCH 136
__launch_bounds__(256)
__global__ void attn(const short* __restrict__ Kb, const short* __restrict__ Qb,
                     const short* __restrict__ Vt, const float* __restrict__ kmax2,
                     float* __restrict__ out) {
  __shared__ char Kld[2][64 * 128];   // [buf][row s][64 f16, swizzled] 8KB each
  __shared__ char Vld[2][64 * 128];   // [buf][row h][64 f16, swizzled] 8KB each
  __shared__ char Pl[4][16 * PPITCH]; // per-wave P buffer [q=c][s packed f16]

  const int tid = threadIdx.x, lane = tid & 63, wave = tid >> 6;
  const int g = lane >> 4, c = lane & 15;
  const int b = blockIdx.x & 7;        // XCD = blockIdx % 8 = batch
  const int qt = blockIdx.x >> 3;
  const int nkv = qt + 1;
  const int q0 = qt * 64;
  const int qg = q0 + wave * 16 + c;   // this lane's q-row (column of S^T)
  const float c2 = 0.125f * 1.44269504088896340736f;

  // Q fragments (B-operand: row=c=q, k-slice kc*32+g*8)
  f16x8 qa[2];
  {
    size_t base = ((size_t)b * NT + (size_t)qg) * HD + (g << 3);
    qa[0] = *(const f16x8*)(Qb + base);
    qa[1] = *(const f16x8*)(Qb + base + 32);
  }
  // fixed per-column max bound m2 = |q_row(c)| * KMAX * c2
  float m2;
  {
    float qn = 0.f;
#pragma unroll
    for (int kc = 0; kc < 2; ++kc)
#pragma unroll
      for (int j = 0; j < 8; ++j) {
        float qv = (float)qa[kc][j];
        qn += qv * qv;
      }
    qn += __shfl_xor(qn, 16);
    qn += __shfl_xor(qn, 32);
    m2 = sqrtf(qn) * sqrtf(kmax2[b]) * c2;
  }

  f32x4 o[4];
#pragma unroll
  for (int nt = 0; nt < 4; ++nt) o[nt] = (f32x4){0.f, 0.f, 0.f, 0.f};
  float l_r = 0.f;

  // staging: wave w covers rows [w*16, w*16+16) of each tile.
  // pre-swizzled source chunk so linear DMA + swizzled ds_read agree.
  const int sub = lane >> 3, chx = (lane & 7) ^ sub;
  const char* ksrc = (const char*)Kb + ((size_t)b * NT) * 128;    // K row pitch 128B
  const char* vsrc = (const char*)Vt + ((size_t)b * HD) * 4096;   // V^T row pitch 4096B
  char* pw = Pl[wave];

  auto STAGE = [&](int t, int p) {
    const int s0 = t * 64;
    const char* kp = ksrc + (size_t)(s0 + wave * 16 + sub) * 128 + (size_t)chx * 16;
    const char* vp = vsrc + (size_t)(wave * 16 + sub) * 4096 + (size_t)s0 * 2 +
                     (size_t)chx * 16;
    gload_lds16(kp, Kld[p] + (wave * 16) * 128);
    gload_lds16(kp + 8 * 128, Kld[p] + (wave * 16 + 8) * 128);
    gload_lds16(vp, Vld[p] + (wave * 16) * 128);
    gload_lds16(vp + (size_t)8 * 4096, Vld[p] + (wave * 16 + 8) * 128);
  };

  STAGE(0, 0);
  __syncthreads();
  int cur = 0;
#pragma unroll 1
  for (int t = 0; t < nkv; ++t) {
    if (t + 1 < nkv) STAGE(t + 1, cur ^ 1);
    const int s0 = t * 64;

    // S^T = K Q^T : D[row=s_local][col=q]
    f32x4 s[4];
#pragma unroll
    for (int st = 0; st < 4; ++st) s[st] = (f32x4){0.f, 0.f, 0.f, 0.f};
#pragma unroll
    for (int kc = 0; kc < 2; ++kc)
#pragma unroll
      for (int st = 0; st < 4; ++st) {
        const int krow = st * 16 + c;
        f16x8 kf = *(const f16x8*)(Kld[cur] + krow * 128 +
                                   ((kc * 64 + (g << 4)) ^ ((krow & 7) << 4)));
        s[st] = __builtin_amdgcn_mfma_f32_16x16x32_f16(kf, qa[kc], s[st], 0, 0, 0);
      }

    // P = exp2(S*c2 - m2), mask if s>q on diagonal tile; pack pairs, store b64
    const bool diag = (t == qt);
#pragma unroll
    for (int st = 0; st < 4; ++st) {
      float pv[4];
#pragma unroll
      for (int i = 0; i < 4; ++i) {
        int sg = s0 + st * 16 + (g << 2) + i;
        float p = __builtin_amdgcn_exp2f(s[st][i] * c2 - m2);
        pv[i] = (diag && sg > qg) ? 0.f : p;
      }
      l_r += (pv[0] + pv[1]) + (pv[2] + pv[3]);
      uint2 w;
      w.x = pk2h(pv[0], pv[1]);
      w.y = pk2h(pv[2], pv[3]);
      *(uint2*)(pw + c * PPITCH + st * 32 + g * 8) = w;
    }

    // O += P V : A = P rows q (read back), B = V^T rows h from LDS
#pragma unroll
    for (int kc = 0; kc < 2; ++kc) {
      uint2 h0 = *(const uint2*)(pw + c * PPITCH + kc * 64 + g * 16);
      uint2 h1 = *(const uint2*)(pw + c * PPITCH + kc * 64 + g * 16 + 8);
      f16x8 pa;
      *(uint2*)&pa = h0;
      *((uint2*)&pa + 1) = h1;
#pragma unroll
      for (int nt = 0; nt < 4; ++nt) {
        const int vrow = nt * 16 + c;
        f16x8 vv = *(const f16x8*)(Vld[cur] + vrow * 128 +
                                   ((kc * 64 + (g << 4)) ^ ((vrow & 7) << 4)));
        o[nt] = __builtin_amdgcn_mfma_f32_16x16x32_f16(pa, vv, o[nt], 0, 0, 0);
      }
    }
    __syncthreads();   // drains stage DMA (vmcnt) + all LDS ops; buffers swap
    cur ^= 1;
  }

  // finish l (sum the 4 g-partials per column), normalize, write out
  l_r += __shfl_xor(l_r, 16);
  l_r += __shfl_xor(l_r, 32);
  float* outb = out + ((size_t)b * NT + (size_t)(q0 + wave * 16)) * HD;
#pragma unroll
  for (int i = 0; i < 4; ++i) {
    int r = (g << 2) + i;
    float inv = 1.0f / __shfl(l_r, r);
#pragma unroll
    for (int nt = 0; nt < 4; ++nt)
      outb[(size_t)r * HD + nt * 16 + c] = o[nt][i] * inv;
  }
}

extern "C" void kernel_launch(void* const* d_in, const int* in_sizes, int n_in,
                              void* d_out, int out_size, void* d_ws, size_t ws_size,
                              hipStream_t stream) {
  const float* x = (const float*)d_in[0];
  const float* W = (const float*)d_in[1];
  const float* bias = (const float*)d_in[2];
  float* out = (float*)d_out;

  char* ws = (char*)d_ws;
  float* kmax2 = (float*)ws;                       // 8 f32
  short* Wt = (short*)(ws + 2048);                 // [192][1024] f16
  short* Kb = Wt + (size_t)N3 * NC;                // [8][2048][64] f16
  short* Qb = Kb + (size_t)NB * NT * HD;           // [8][2048][64] f16
  short* Vt = Qb + (size_t)NB * NT * HD;           // [8][64][2048] f16

  prep_w<<<64, 256, 0, stream>>>(W, Wt, kmax2);
  qkv_proj<<<512, 256, 0, stream>>>(x, Wt, bias, Kb, Qb, Vt, kmax2);
  attn<<<NB * 32, 256, 0, stream>>>(Kb, Qb, Vt, kmax2, out);
}